// Round 6
// baseline (257.602 us; speedup 1.0000x reference)
//
#include <hip/hip_runtime.h>

// LIF forward recurrence:
//   mem0 = x[0]; spike0 = (mem0 > 0.5)
//   mem_t = mem_{t-1} * 0.25 * (1 - spike_{t-1}) + x_t ; spike_t = (mem_t > 0.5)
// Output: spikes [T, B, D] float32.
//
// R1-R5 post-mortem: every structure that interleaves loads and stores pins
// at ~2.4 TB/s. CDNA has ONE vmcnt FIFO for loads AND stores, retired in
// order -> any load-wait behind a store also waits for the store's ack, and
// store-acks under 134 MB of write pressure are slow. R6 (H3 test): issue ALL
// 32 loads before ANY store. FIFO order then guarantees a wait for load k
// (vmcnt(31-k)) retires only loads; store acks are never on the critical
// path. 32 x float4 buffer = 128 VGPRs; __launch_bounds__(256,1) gives the
// allocator room; sched_barrier(0) pins the load block ahead of the
// compute/store block.
//
// t=0 folds into the recurrence via mem=0, s=0 (0*anything + x0 = x0).
// Arithmetic note: DECAY*(1-s) in {0.25, 0} and mem*0.25 are exact, so
// fma(mem, DECAY*(1-s), x) rounds identically to the reference -> absmax 0.

constexpr int   T_STEPS = 32;
constexpr float THRESH  = 0.5f;
constexpr float DECAY   = 0.25f;

__global__ __launch_bounds__(256, 1) void lif_fwd_kernel(
    const float4* __restrict__ x,   // [T, n4]
    float4* __restrict__ out,       // [T, n4]
    int n4)
{
    const int i = blockIdx.x * 256 + threadIdx.x;
    if (i >= n4) return;

    const float4* xp = x + i;
    float4*       op = out + i;

    // Phase 1: all 32 independent loads into registers. 32 KiB/wave in
    // flight; nothing here depends on anything -> back-to-back issue.
    float4 v[T_STEPS];
#pragma unroll
    for (int t = 0; t < T_STEPS; ++t)
        v[t] = xp[t * n4];

    // Hard scheduling fence: no instruction (in particular no store) may be
    // hoisted above, and no load may be sunk below. All loads precede all
    // stores in the vmcnt FIFO.
    __builtin_amdgcn_sched_barrier(0);

    // Phase 2: recurrence + stores. The compiler's s_waitcnt before v[t]'s
    // first use is vmcnt(31-t): with only loads ahead of it in the FIFO,
    // it never waits on a store ack.
    float4 mem = {0.0f, 0.0f, 0.0f, 0.0f};
    float4 s   = {0.0f, 0.0f, 0.0f, 0.0f};
#pragma unroll
    for (int t = 0; t < T_STEPS; ++t) {
        mem.x = mem.x * (DECAY * (1.0f - s.x)) + v[t].x;
        mem.y = mem.y * (DECAY * (1.0f - s.y)) + v[t].y;
        mem.z = mem.z * (DECAY * (1.0f - s.z)) + v[t].z;
        mem.w = mem.w * (DECAY * (1.0f - s.w)) + v[t].w;
        s.x = mem.x > THRESH ? 1.0f : 0.0f;
        s.y = mem.y > THRESH ? 1.0f : 0.0f;
        s.z = mem.z > THRESH ? 1.0f : 0.0f;
        s.w = mem.w > THRESH ? 1.0f : 0.0f;
        op[t * n4] = s;
    }
}

extern "C" void kernel_launch(void* const* d_in, const int* in_sizes, int n_in,
                              void* d_out, int out_size, void* d_ws, size_t ws_size,
                              hipStream_t stream) {
    const float* x = (const float*)d_in[0];
    float* out = (float*)d_out;

    const int total = in_sizes[0];        // T * B * D = 33_554_432
    const int n     = total / T_STEPS;    // B * D     = 1_048_576
    const int n4    = n / 4;              // 262_144 float4 lanes

    const int block = 256;
    const int grid  = (n4 + block - 1) / block;  // 1024 blocks

    lif_fwd_kernel<<<grid, block, 0, stream>>>(
        reinterpret_cast<const float4*>(x),
        reinterpret_cast<float4*>(out),
        n4);
}

// Round 7
// 236.826 us; speedup vs baseline: 1.0877x; 1.0877x over previous
//
#include <hip/hip_runtime.h>

// LIF forward recurrence:
//   mem0 = x[0]; spike0 = (mem0 > 0.5)
//   mem_t = mem_{t-1} * 0.25 * (1 - spike_{t-1}) + x_t ; spike_t = (mem_t > 0.5)
// Output: spikes [T, B, D] float32.
//
// R1-R6 post-mortem: every single-kernel structure pins at ~2.4 TB/s while
// fillBuffer hits 6.5. Invariant cause: 64 concurrent 4MiB-strided streams
// per wave; 4MiB stride aliases all planes onto the same channels -> DRAM
// row-buffer thrash (streams >> banks/channel). R7: split T into 4 chunks of
// 8 -> ~17 streams/wave (copy-like), carrying only `mem` between sub-kernels
// (spike is recomputed as mem>0.5, not carried). +25 MB carry traffic (+12%),
// 4 sequential in-graph launches on one stream (carry makes them dependent).
//
// t=0 folds into the recurrence via mem=0, s=0 (0*anything + x0 = x0).
// All arithmetic matches the reference bitwise (x*0.25 exact, gate in {0,1}).

constexpr float THRESH = 0.5f;
constexpr float DECAY  = 0.25f;

template <int T0, int TN, bool WRITE_CARRY>
__global__ __launch_bounds__(256) void lif_chunk_kernel(
    const float4* __restrict__ x,     // [32, n4]
    float4* __restrict__ out,         // [32, n4]
    float4* __restrict__ carry,       // [n4] mem carry in workspace
    int n4)
{
    const int i = blockIdx.x * 256 + threadIdx.x;
    if (i >= n4) return;

    float4 mem, s;
    if (T0 == 0) {
        mem = {0.0f, 0.0f, 0.0f, 0.0f};   // step 0 then yields mem = x[0]
        s   = {0.0f, 0.0f, 0.0f, 0.0f};
    } else {
        mem = carry[i];                    // spike is a function of mem
        s.x = mem.x > THRESH ? 1.0f : 0.0f;
        s.y = mem.y > THRESH ? 1.0f : 0.0f;
        s.z = mem.z > THRESH ? 1.0f : 0.0f;
        s.w = mem.w > THRESH ? 1.0f : 0.0f;
    }

#pragma unroll
    for (int t = 0; t < TN; ++t) {
        float4 v = x[(T0 + t) * n4 + i];
        mem.x = mem.x * (DECAY * (1.0f - s.x)) + v.x;
        mem.y = mem.y * (DECAY * (1.0f - s.y)) + v.y;
        mem.z = mem.z * (DECAY * (1.0f - s.z)) + v.z;
        mem.w = mem.w * (DECAY * (1.0f - s.w)) + v.w;
        s.x = mem.x > THRESH ? 1.0f : 0.0f;
        s.y = mem.y > THRESH ? 1.0f : 0.0f;
        s.z = mem.z > THRESH ? 1.0f : 0.0f;
        s.w = mem.w > THRESH ? 1.0f : 0.0f;
        out[(T0 + t) * n4 + i] = s;
    }

    if (WRITE_CARRY)
        carry[i] = mem;
}

extern "C" void kernel_launch(void* const* d_in, const int* in_sizes, int n_in,
                              void* d_out, int out_size, void* d_ws, size_t ws_size,
                              hipStream_t stream) {
    const float4* x     = reinterpret_cast<const float4*>(d_in[0]);
    float4*       out   = reinterpret_cast<float4*>(d_out);
    float4*       carry = reinterpret_cast<float4*>(d_ws);   // 4 MB of ws

    const int total = in_sizes[0];   // 32 * B * D = 33_554_432
    const int n     = total / 32;    // B * D      = 1_048_576
    const int n4    = n / 4;         // 262_144 float4 columns

    const int block = 256;
    const int grid  = (n4 + block - 1) / block;   // 1024 blocks

    // 4 dependent sub-kernels on one stream; only `mem` crosses boundaries.
    lif_chunk_kernel< 0, 8, true ><<<grid, block, 0, stream>>>(x, out, carry, n4);
    lif_chunk_kernel< 8, 8, true ><<<grid, block, 0, stream>>>(x, out, carry, n4);
    lif_chunk_kernel<16, 8, true ><<<grid, block, 0, stream>>>(x, out, carry, n4);
    lif_chunk_kernel<24, 8, false><<<grid, block, 0, stream>>>(x, out, carry, n4);
}